// Round 8
// baseline (412.061 us; speedup 1.0000x reference)
//
#include <hip/hip_runtime.h>
#include <hip/hip_bf16.h>
#include <math.h>

#define B_ 64
#define C_ 512
#define N_ 1024
#define D_ 128
#define K_ 8

typedef __attribute__((ext_vector_type(8))) short bf16x8;  // 8 bf16 = 4 VGPRs
typedef __attribute__((ext_vector_type(4))) float f32x4;
typedef unsigned short ushort_t;

__device__ __forceinline__ unsigned short f2bs(float f) {
    union { __hip_bfloat16 h; unsigned short s; } u;
    u.h = __float2bfloat16(f);
    return u.s;
}
__device__ __forceinline__ float bs2f(unsigned short s) {
    union { unsigned int u; float f; } v;
    v.u = ((unsigned int)s) << 16;
    return v.f;
}
__device__ __forceinline__ float sigmoidf_(float x) { return 1.0f / (1.0f + expf(-x)); }
__device__ __forceinline__ float gelu_exact(float x) {
    return 0.5f * x * (1.0f + erff(x * 0.7071067811865476f));
}

// ---------------------------------------------------------------------------
// K0: weight prep (blocks 0-255) + slots init / iter-0 q (blocks 256-511).
// Unchanged, proven round 7.
// ---------------------------------------------------------------------------
__global__ __launch_bounds__(256) void prep_init(
    const float* __restrict__ Wp, const float* __restrict__ Wk,
    const float* __restrict__ Wv, const float* __restrict__ W_ih,
    const float* __restrict__ W_hh,
    const float* __restrict__ noise, const float* __restrict__ mu,
    const float* __restrict__ lsig,
    const float* __restrict__ g_slots, const float* __restrict__ b_slots,
    const float* __restrict__ Wq, const float* __restrict__ bq,
    ushort_t* __restrict__ WpT, ushort_t* __restrict__ WkT,
    ushort_t* __restrict__ WvT, float* __restrict__ WTih,
    float* __restrict__ WThh,
    float* __restrict__ slots, float* __restrict__ qbuf)
{
    __shared__ float sl2[2][128];
    __shared__ float tt2[2][128];
    __shared__ float mrs2[2][2];
    const int t = threadIdx.x;

    if (blockIdx.x < 256) {
        int tid = blockIdx.x * 256 + t;             // 0..65535
        {
            int c = tid >> 7, d = tid & 127;        // coalesced read of Wp
            WpT[d * 512 + c] = f2bs(Wp[tid]);
        }
        if (tid < 16384) {
            int c = tid >> 7, d = tid & 127;
            WkT[d * 128 + c] = f2bs(Wk[tid]);
            WvT[d * 128 + c] = f2bs(Wv[tid]);
        }
        if (tid < 49152) {
            int j = tid >> 7, c = tid & 127;        // coalesced read of W_ih
            WTih[c * 384 + j] = W_ih[tid];
            WThh[c * 384 + j] = W_hh[tid];
        }
        return;
    }

    const int lr = t >> 7, lt = t & 127;
    const int row = ((blockIdx.x - 256) << 1) | lr;   // 0..511 = b*8+k
    const int b = row >> 3;
    const int kd = (row & 7) * 128 + lt;
    float sv = mu[kd] + expf(lsig[kd]) * noise[b * 1024 + kd];
    slots[(size_t)row * D_ + lt] = sv;
    sl2[lr][lt] = sv;
    __syncthreads();
    if (lt < 64) {
        float v0 = sl2[lr][lt], v1 = sl2[lr][lt + 64];
        float s = v0 + v1, s2 = v0 * v0 + v1 * v1;
        for (int off = 32; off > 0; off >>= 1) {
            s += __shfl_down(s, off, 64);
            s2 += __shfl_down(s2, off, 64);
        }
        if (lt == 0) {
            float mean = s * (1.f / 128.f);
            float var = s2 * (1.f / 128.f) - mean * mean;
            mrs2[lr][0] = mean; mrs2[lr][1] = rsqrtf(var + 1e-5f);
        }
    }
    __syncthreads();
    tt2[lr][lt] = (sl2[lr][lt] - mrs2[lr][0]) * mrs2[lr][1] * g_slots[lt] + b_slots[lt];
    __syncthreads();
    float a = bq[lt];
    for (int c = 0; c < 128; ++c) a = fmaf(tt2[lr][c], Wq[(size_t)c * D_ + lt], a);
    qbuf[(size_t)row * D_ + lt] = a;
}

// ---------------------------------------------------------------------------
// K1+K2 fused, v2. Phase 1 now loads MFMA fragments DIRECTLY from global:
//   A: 8 scalar x-loads per fragment, converted in-register (64B segments;
//      r=0/r=1 fragments cover both halves of each 128B line -> L1-served).
//   B: one aligned bf16x8 from WpT (128KB, L2-resident after first block).
// This removes ALL phase-1 LDS staging (the measured 1.1e7-cycle 16-way
// bank conflict) and all 32 chunk barriers -> compiler pipelines VMEM/MFMA.
// Values bit-identical to the staged version (same f2bs, same MFMA order).
// Phase 2 (k/v from LDS A2) unchanged, proven round 7.
// ---------------------------------------------------------------------------
__global__ __launch_bounds__(256) void proj_kv(
    const float* __restrict__ x, const ushort_t* __restrict__ WpT,
    const float* __restrict__ bp, const float* __restrict__ g_in,
    const float* __restrict__ b_in,
    const ushort_t* __restrict__ WkT, const float* __restrict__ bk,
    const ushort_t* __restrict__ WvT, const float* __restrict__ bv,
    ushort_t* __restrict__ kout, ushort_t* __restrict__ vout)
{
    __shared__ __align__(16) ushort_t Bl[128 * 40];   // WkT chunks (phase 2)
    __shared__ __align__(16) ushort_t Bv2[128 * 40];  // WvT chunks (phase 2)
    __shared__ __align__(16) ushort_t A2[64 * 136];   // LN'd inputs, bf16
    __shared__ float red[64][2][2];
    const int t = threadIdx.x;
    const int b = blockIdx.x >> 4;
    const int n0 = (blockIdx.x & 15) << 6;
    const int w = t >> 6, lane = t & 63;
    const int quad = lane >> 4, m = lane & 15;
    const int rowoff = (w >> 1) << 5;   // 0 / 32
    const int coloff = (w & 1) << 6;    // 0 / 64

    // ================= phase 1: proj + LN, zero-LDS main loop ==============
    f32x4 acc[2][4];
#pragma unroll
    for (int r = 0; r < 2; ++r)
#pragma unroll
        for (int c = 0; c < 4; ++c) acc[r][c] = (f32x4){0.f, 0.f, 0.f, 0.f};

    const float* xb = x + (size_t)b * (C_ * N_);
    for (int c0 = 0; c0 < C_; c0 += 32) {
        bf16x8 af[2], bfr[4];
#pragma unroll
        for (int r = 0; r < 2; ++r) {
            union { ushort_t u[8]; bf16x8 v; } pk;
            const int row = n0 + rowoff + 16 * r + m;
#pragma unroll
            for (int j = 0; j < 8; ++j)
                pk.u[j] = f2bs(xb[(size_t)(c0 + quad * 8 + j) * N_ + row]);
            af[r] = pk.v;
        }
#pragma unroll
        for (int c = 0; c < 4; ++c)
            bfr[c] = *(const bf16x8*)&WpT[(size_t)(coloff + 16 * c + m) * 512 + c0 + quad * 8];
#pragma unroll
        for (int r = 0; r < 2; ++r)
#pragma unroll
            for (int c = 0; c < 4; ++c)
                acc[r][c] = __builtin_amdgcn_mfma_f32_16x16x32_bf16(af[r], bfr[c], acc[r][c], 0, 0, 0);
    }
    float gv[4], bvv[4], bpv[4];
#pragma unroll
    for (int c = 0; c < 4; ++c) {
        int col = coloff + 16 * c + m;
        bpv[c] = bp[col]; gv[c] = g_in[col]; bvv[c] = b_in[col];
    }
#pragma unroll
    for (int r = 0; r < 2; ++r)
#pragma unroll
        for (int c = 0; c < 4; ++c)
#pragma unroll
            for (int g = 0; g < 4; ++g) acc[r][c][g] += bpv[c];

#pragma unroll
    for (int r = 0; r < 2; ++r) {
#pragma unroll
        for (int g = 0; g < 4; ++g) {
            float s = 0.f, s2 = 0.f;
#pragma unroll
            for (int c = 0; c < 4; ++c) { float v = acc[r][c][g]; s += v; s2 += v * v; }
#pragma unroll
            for (int off = 1; off < 16; off <<= 1) {
                s += __shfl_xor(s, off, 64);
                s2 += __shfl_xor(s2, off, 64);
            }
            if (m == 0) {
                int row = rowoff + 16 * r + quad * 4 + g;
                red[row][w & 1][0] = s;
                red[row][w & 1][1] = s2;
            }
        }
    }
    __syncthreads();
#pragma unroll
    for (int r = 0; r < 2; ++r) {
#pragma unroll
        for (int g = 0; g < 4; ++g) {
            int row = rowoff + 16 * r + quad * 4 + g;
            float s = red[row][0][0] + red[row][1][0];
            float s2 = red[row][0][1] + red[row][1][1];
            float mean = s * (1.f / 128.f);
            float var = s2 * (1.f / 128.f) - mean * mean;
            float rs = rsqrtf(var + 1e-5f);
#pragma unroll
            for (int c = 0; c < 4; ++c) {
                int col = coloff + 16 * c + m;
                float v = (acc[r][c][g] - mean) * rs * gv[c] + bvv[c];
                A2[row * 136 + col] = f2bs(v);
            }
        }
    }
    // A2 writes synced by the first barrier of phase 2.

    // ================= phase 2: k/v MFMA (proven) =========================
    const int is_v = w >> 1;
    const int rowoff2 = (w & 1) << 5;
    f32x4 acc2[2][8];
#pragma unroll
    for (int r = 0; r < 2; ++r)
#pragma unroll
        for (int c = 0; c < 8; ++c) acc2[r][c] = (f32x4){0.f, 0.f, 0.f, 0.f};

    for (int c0 = 0; c0 < D_; c0 += 32) {
#pragma unroll
        for (int i = 0; i < 2; ++i) {
            int idx = t + (i << 8);
            int d = idx >> 2, seg = idx & 3;
            *(bf16x8*)&Bl[d * 40 + seg * 8] =
                *(const bf16x8*)&WkT[d * 128 + c0 + seg * 8];
            *(bf16x8*)&Bv2[d * 40 + seg * 8] =
                *(const bf16x8*)&WvT[d * 128 + c0 + seg * 8];
        }
        __syncthreads();
        const ushort_t* Bsrc = is_v ? Bv2 : Bl;
        bf16x8 af[2], bfr[8];
#pragma unroll
        for (int r = 0; r < 2; ++r)
            af[r] = *(const bf16x8*)&A2[(rowoff2 + 16 * r + m) * 136 + c0 + quad * 8];
#pragma unroll
        for (int c = 0; c < 8; ++c)
            bfr[c] = *(const bf16x8*)&Bsrc[(16 * c + m) * 40 + quad * 8];
#pragma unroll
        for (int r = 0; r < 2; ++r)
#pragma unroll
            for (int c = 0; c < 8; ++c)
                acc2[r][c] = __builtin_amdgcn_mfma_f32_16x16x32_bf16(af[r], bfr[c], acc2[r][c], 0, 0, 0);
        __syncthreads();
    }
    const float* bias = is_v ? bv : bk;
    ushort_t* dst = is_v ? vout : kout;
    float bval[8];
#pragma unroll
    for (int c = 0; c < 8; ++c) bval[c] = bias[16 * c + m];
#pragma unroll
    for (int r = 0; r < 2; ++r) {
#pragma unroll
        for (int g = 0; g < 4; ++g) {
            int row = rowoff2 + 16 * r + quad * 4 + g;
            size_t base = ((size_t)b * N_ + n0 + row) * D_;
#pragma unroll
            for (int c = 0; c < 8; ++c)
                dst[base + 16 * c + m] = f2bs(acc2[r][c][g] + bval[c]);
        }
    }
}

// ---------------------------------------------------------------------------
// K4: attn + PV per n-quarter. Round-6-proven structure; kvt now pitch-128
// with XOR block swizzle (block ^= row&15) applied to BOTH stagings and BOTH
// read sites (same involution write/read). Fixes the 8-way bank conflict on
// the logits ds_read_b128 (64 consecutive-row lanes previously hit 8 banks).
// ---------------------------------------------------------------------------
__global__ __launch_bounds__(512, 2) void attn_pv(
    const ushort_t* __restrict__ kb, const ushort_t* __restrict__ vb,
    const float* __restrict__ qbuf,
    float* __restrict__ S_part, float* __restrict__ upd_part,
    float* __restrict__ out_attn, int last)
{
    __shared__ __align__(16) char scratch[69632];   // kvt[256][128] ush U red[64][132] f32
    __shared__ __align__(16) float at8[8][264];     // logits -> attn (quarter)
    __shared__ __align__(16) float qs[8][132];
    __shared__ float red2[4][8];
    ushort_t* kvt = (ushort_t*)scratch;
    float* red = (float*)scratch;

    const int t = threadIdx.x;
    const int qd = blockIdx.x, b = blockIdx.y;
    const int nbase = qd << 8;
    const int wv = t >> 6, lane = t & 63;
    const float SCALE = 0.08838834764831845f;

    // q: 4 KB, coalesced
    for (int i = t; i < 1024; i += 512)
        qs[i >> 7][i & 127] = qbuf[(size_t)b * 1024 + i];
    // stage k-quarter (coalesced bf16x8, swizzled dest)
#pragma unroll
    for (int i = 0; i < 8; ++i) {
        int idx = t + (i << 9);            // 0..4095
        int rr = idx >> 4, u8 = (idx & 15) << 3;
        int su8 = u8 ^ ((rr & 15) << 3);
        *(bf16x8*)&kvt[rr * 128 + su8] =
            *(const bf16x8*)&kb[((size_t)b * N_ + nbase + rr) * D_ + u8];
    }
    __syncthreads();

    // logits: thread (rr = t&255, kh = t>>8) -> 4 k-dots for its n-row
    {
        const int rr = t & 255, kh = t >> 8;
        float acc[4] = {0.f, 0.f, 0.f, 0.f};
        for (int c0 = 0; c0 < 128; c0 += 8) {
            bf16x8 kr = *(const bf16x8*)&kvt[rr * 128 + (c0 ^ ((rr & 15) << 3))];
            float kf[8];
#pragma unroll
            for (int j = 0; j < 8; ++j) kf[j] = bs2f((ushort_t)kr[j]);
#pragma unroll
            for (int kk = 0; kk < 4; ++kk) {
                f32x4 qa = *(const f32x4*)&qs[4 * kh + kk][c0];
                f32x4 qb = *(const f32x4*)&qs[4 * kh + kk][c0 + 4];
                acc[kk] = fmaf(qa[0], kf[0], acc[kk]);
                acc[kk] = fmaf(qa[1], kf[1], acc[kk]);
                acc[kk] = fmaf(qa[2], kf[2], acc[kk]);
                acc[kk] = fmaf(qa[3], kf[3], acc[kk]);
                acc[kk] = fmaf(qb[0], kf[4], acc[kk]);
                acc[kk] = fmaf(qb[1], kf[5], acc[kk]);
                acc[kk] = fmaf(qb[2], kf[6], acc[kk]);
                acc[kk] = fmaf(qb[3], kf[7], acc[kk]);
            }
        }
#pragma unroll
        for (int kk = 0; kk < 4; ++kk)
            at8[4 * kh + kk][rr] = acc[kk];
    }
    __syncthreads();

    // softmax over k per local n (t<256) + per-wave S partials
    if (t < 256) {
        float l[8];
#pragma unroll
        for (int k = 0; k < 8; ++k) l[k] = at8[k][t] * SCALE;
        float mx = l[0];
#pragma unroll
        for (int k = 1; k < 8; ++k) mx = fmaxf(mx, l[k]);
        float e[8], ssum = 0.f;
#pragma unroll
        for (int k = 0; k < 8; ++k) { e[k] = expf(l[k] - mx); ssum += e[k]; }
        float inv = 1.f / ssum;
        float p[8];
#pragma unroll
        for (int k = 0; k < 8; ++k) {
            p[k] = e[k] * inv;
            at8[k][t] = p[k];
            if (last) out_attn[((size_t)b * K_ + k) * N_ + nbase + t] = p[k];
        }
#pragma unroll
        for (int k = 0; k < 8; ++k) {
            float v = p[k];
            for (int off = 32; off > 0; off >>= 1) v += __shfl_down(v, off, 64);
            if (lane == 0) red2[wv][k] = v;
        }
    }
    __syncthreads();
    if (t < 8)
        S_part[((size_t)b * 4 + qd) * 8 + t] =
            red2[0][t] + red2[1][t] + red2[2][t] + red2[3][t];

    // stage v-quarter (kvt reuse, same swizzle)
#pragma unroll
    for (int i = 0; i < 8; ++i) {
        int idx = t + (i << 9);
        int rr = idx >> 4, u8 = (idx & 15) << 3;
        int su8 = u8 ^ ((rr & 15) << 3);
        *(bf16x8*)&kvt[rr * 128 + su8] =
            *(const bf16x8*)&vb[((size_t)b * N_ + nbase + rr) * D_ + u8];
    }
    __syncthreads();

    // PV: upd quarter-partial = attn(quarter) @ v(quarter)
    {
        float acc[8][4];
#pragma unroll
        for (int k = 0; k < 8; ++k)
#pragma unroll
            for (int j = 0; j < 4; ++j) acc[k][j] = 0.f;
        const int d4 = (t & 31) * 4, s = t >> 5;
#pragma unroll
        for (int i2 = 0; i2 < 4; ++i2) {
            const int nn = (s << 4) + (i2 << 2);
            float vf[4][4];
#pragma unroll
            for (int i = 0; i < 4; ++i) {
                int row = nn + i;
                int scol = (d4 & 7) | ((d4 & 0x78) ^ ((row & 15) << 3));
                ushort4 v4 = *(const ushort4*)&kvt[row * 128 + scol];
                vf[i][0] = bs2f(v4.x); vf[i][1] = bs2f(v4.y);
                vf[i][2] = bs2f(v4.z); vf[i][3] = bs2f(v4.w);
            }
#pragma unroll
            for (int k = 0; k < 8; ++k) {
                f32x4 a4 = *(const f32x4*)&at8[k][nn];
#pragma unroll
                for (int i = 0; i < 4; ++i) {
                    acc[k][0] = fmaf(a4[i], vf[i][0], acc[k][0]);
                    acc[k][1] = fmaf(a4[i], vf[i][1], acc[k][1]);
                    acc[k][2] = fmaf(a4[i], vf[i][2], acc[k][2]);
                    acc[k][3] = fmaf(a4[i], vf[i][3], acc[k][3]);
                }
            }
        }
        __syncthreads();   // kvt reads done; scratch becomes red[]
#pragma unroll
        for (int k = 0; k < 8; ++k)
#pragma unroll
            for (int j = 0; j < 4; ++j)
                acc[k][j] += __shfl_xor(acc[k][j], 32, 64);
        if (lane < 32) {
#pragma unroll
            for (int k = 0; k < 8; ++k)
#pragma unroll
                for (int j = 0; j < 4; ++j)
                    red[(wv * 8 + k) * 132 + lane * 4 + j] = acc[k][j];
        }
        __syncthreads();
        for (int i = t; i < 1024; i += 512) {
            int k = i >> 7, d = i & 127;
            float ssum = 0.f;
#pragma unroll
            for (int w = 0; w < 8; ++w) ssum += red[(w * 8 + k) * 132 + d];
            upd_part[((size_t)b * 4 + qd) * 1024 + i] = ssum;
        }
    }
}

// ---------------------------------------------------------------------------
// K5: GRU + LN + MLP + residual + next-q (unchanged, proven round 6/7).
// ---------------------------------------------------------------------------
__global__ __launch_bounds__(256) void gru_mlp_q(
    const float* __restrict__ upd_part, const float* __restrict__ S_part,
    float* __restrict__ slots,
    const float* __restrict__ WTih, const float* __restrict__ WThh,
    const float* __restrict__ b_ih, const float* __restrict__ b_hh,
    const float* __restrict__ W1, const float* __restrict__ b1,
    const float* __restrict__ W2, const float* __restrict__ b2,
    const float* __restrict__ g_mlp, const float* __restrict__ b_mlp,
    const float* __restrict__ g_slots, const float* __restrict__ b_slots,
    const float* __restrict__ Wq, const float* __restrict__ bq,
    float* __restrict__ qbuf,
    float* __restrict__ out_slots, int final_iter)
{
    __shared__ float u[128], h[128], gx[384], gh[384], sn[128], tt[128], hm[256];
    __shared__ float mrs[2];
    const int t = threadIdx.x;
    const int row = blockIdx.x;           // b*8 + k
    const int b = row >> 3, k = row & 7;
    if (t < 128) {
        size_t sb = (size_t)b * 4;
        float S = S_part[(sb + 0) * 8 + k] + S_part[(sb + 1) * 8 + k]
                + S_part[(sb + 2) * 8 + k] + S_part[(sb + 3) * 8 + k];
        float inv = 1.0f / (S + 1e-8f);
        int i = k * 128 + t;
        float up = upd_part[(sb + 0) * 1024 + i] + upd_part[(sb + 1) * 1024 + i]
                 + upd_part[(sb + 2) * 1024 + i] + upd_part[(sb + 3) * 1024 + i];
        u[t] = up * inv;
        h[t] = slots[(size_t)row * D_ + t];
    }
    __syncthreads();
    {
        int j = t;
        float ax = 0.f, ah = 0.f;
        for (int c = 0; c < 128; ++c) {
            float uc = u[c], hc = h[c];
            ax = fmaf(uc, WTih[(size_t)c * 384 + j], ax);
            ah = fmaf(hc, WThh[(size_t)c * 384 + j], ah);
        }
        gx[j] = ax + b_ih[j];
        gh[j] = ah + b_hh[j];
    }
    if (t < 128) {
        int j = 256 + t;
        float ax = 0.f, ah = 0.f;
        for (int c = 0; c < 128; ++c) {
            float uc = u[c], hc = h[c];
            ax = fmaf(uc, WTih[(size_t)c * 384 + j], ax);
            ah = fmaf(hc, WThh[(size_t)c * 384 + j], ah);
        }
        gx[j] = ax + b_ih[j];
        gh[j] = ah + b_hh[j];
    }
    __syncthreads();
    if (t < 128) {
        float r = sigmoidf_(gx[t] + gh[t]);
        float z = sigmoidf_(gx[t + 128] + gh[t + 128]);
        float nv = tanhf(gx[t + 256] + r * gh[t + 256]);
        sn[t] = (1.0f - z) * nv + z * h[t];
    }
    __syncthreads();
    if (t < 64) {
        float v0 = sn[t], v1 = sn[t + 64];
        float s = v0 + v1, s2 = v0 * v0 + v1 * v1;
        for (int off = 32; off > 0; off >>= 1) {
            s += __shfl_down(s, off, 64);
            s2 += __shfl_down(s2, off, 64);
        }
        if (t == 0) {
            float mean = s * (1.f / 128.f);
            float var = s2 * (1.f / 128.f) - mean * mean;
            mrs[0] = mean; mrs[1] = rsqrtf(var + 1e-5f);
        }
    }
    __syncthreads();
    if (t < 128) tt[t] = (sn[t] - mrs[0]) * mrs[1] * g_mlp[t] + b_mlp[t];
    __syncthreads();
    {
        float a = 0.f;
        for (int c = 0; c < 128; ++c) a = fmaf(tt[c], W1[(size_t)c * 256 + t], a);
        hm[t] = gelu_exact(a + b1[t]);
    }
    __syncthreads();
    if (t < 128) {
        float a = sn[t] + b2[t];
        for (int j = 0; j < 256; ++j) a = fmaf(hm[j], W2[(size_t)j * D_ + t], a);
        slots[(size_t)row * D_ + t] = a;
        if (final_iter) out_slots[(size_t)row * D_ + t] = a;
        u[t] = a;                      // reuse u[] as new-slots buffer for q
    }
    __syncthreads();
    // ---- q for next iteration
    if (t < 64) {
        float v0 = u[t], v1 = u[t + 64];
        float s = v0 + v1, s2 = v0 * v0 + v1 * v1;
        for (int off = 32; off > 0; off >>= 1) {
            s += __shfl_down(s, off, 64);
            s2 += __shfl_down(s2, off, 64);
        }
        if (t == 0) {
            float mean = s * (1.f / 128.f);
            float var = s2 * (1.f / 128.f) - mean * mean;
            mrs[0] = mean; mrs[1] = rsqrtf(var + 1e-5f);
        }
    }
    __syncthreads();
    if (t < 128) tt[t] = (u[t] - mrs[0]) * mrs[1] * g_slots[t] + b_slots[t];
    __syncthreads();
    if (!final_iter && t < 128) {
        float a = bq[t];
        for (int c = 0; c < 128; ++c) a = fmaf(tt[c], Wq[(size_t)c * D_ + t], a);
        qbuf[(size_t)row * D_ + t] = a;
    }
}

// ---------------------------------------------------------------------------
extern "C" void kernel_launch(void* const* d_in, const int* in_sizes, int n_in,
                              void* d_out, int out_size, void* d_ws, size_t ws_size,
                              hipStream_t stream) {
    const float* x       = (const float*)d_in[0];
    const float* noise   = (const float*)d_in[1];
    const float* slot_mu = (const float*)d_in[2];
    const float* slot_ls = (const float*)d_in[3];
    const float* Wp      = (const float*)d_in[4];
    const float* bp      = (const float*)d_in[5];
    const float* g_in    = (const float*)d_in[6];
    const float* b_in    = (const float*)d_in[7];
    const float* Wq      = (const float*)d_in[8];
    const float* bq      = (const float*)d_in[9];
    const float* Wk      = (const float*)d_in[10];
    const float* bk      = (const float*)d_in[11];
    const float* Wv      = (const float*)d_in[12];
    const float* bv      = (const float*)d_in[13];
    const float* W_ih    = (const float*)d_in[14];
    const float* W_hh    = (const float*)d_in[15];
    const float* b_ih    = (const float*)d_in[16];
    const float* b_hh    = (const float*)d_in[17];
    const float* W1      = (const float*)d_in[18];
    const float* b1      = (const float*)d_in[19];
    const float* W2      = (const float*)d_in[20];
    const float* b2      = (const float*)d_in[21];
    const float* g_slots = (const float*)d_in[22];
    const float* b_slots = (const float*)d_in[23];
    const float* g_mlp   = (const float*)d_in[24];
    const float* b_mlp   = (const float*)d_in[25];

    float* out_slots = (float*)d_out;            // [64,8,128] fp32
    float* out_attn  = (float*)d_out + 65536;    // [64,8,1024] fp32

    // workspace layout (float units)
    float* wsf = (float*)d_ws;
    ushort_t* kb = (ushort_t*)(wsf + 4194304);             // 65536x128 bf16
    ushort_t* vb = (ushort_t*)(wsf + 8388608);             // 65536x128 bf16
    float* slots    = wsf + 12582912;   // 512*128
    float* qbuf     = wsf + 12648448;   // 512*128
    float* upd_part = wsf + 12713984;   // [64][4][8][128] = 262144
    float* S_part   = wsf + 12976128;   // [64][4][8] = 2048
    ushort_t* WpT = (ushort_t*)(wsf + 13304320);  // 128x512 bf16
    ushort_t* WkT = (ushort_t*)(wsf + 13337088);  // 128x128 bf16
    ushort_t* WvT = (ushort_t*)(wsf + 13345280);  // 128x128 bf16
    float* WTih = wsf + 13353472;    // 128x384 fp32
    float* WThh = wsf + 13402624;    // 128x384 fp32

    prep_init<<<dim3(512), dim3(256), 0, stream>>>(
        Wp, Wk, Wv, W_ih, W_hh, noise, slot_mu, slot_ls,
        g_slots, b_slots, Wq, bq,
        WpT, WkT, WvT, WTih, WThh, slots, qbuf);
    proj_kv<<<dim3(1024), dim3(256), 0, stream>>>(
        x, WpT, bp, g_in, b_in, WkT, bk, WvT, bv, kb, vb);

    for (int it = 0; it < 3; ++it) {
        int last = (it == 2) ? 1 : 0;
        attn_pv<<<dim3(4, 64), dim3(512), 0, stream>>>(
            kb, vb, qbuf, S_part, upd_part, out_attn, last);
        gru_mlp_q<<<dim3(512), dim3(256), 0, stream>>>(
            upd_part, S_part, slots, WTih, WThh, b_ih, b_hh,
            W1, b1, W2, b2, g_mlp, b_mlp, g_slots, b_slots,
            Wq, bq, qbuf, out_slots, last);
    }
}

// Round 9
// 396.148 us; speedup vs baseline: 1.0402x; 1.0402x over previous
//
#include <hip/hip_runtime.h>
#include <hip/hip_bf16.h>
#include <math.h>

#define B_ 64
#define C_ 512
#define N_ 1024
#define D_ 128
#define K_ 8

typedef __attribute__((ext_vector_type(8))) short bf16x8;  // 8 bf16 = 4 VGPRs
typedef __attribute__((ext_vector_type(4))) float f32x4;
typedef unsigned short ushort_t;

__device__ __forceinline__ unsigned short f2bs(float f) {
    union { __hip_bfloat16 h; unsigned short s; } u;
    u.h = __float2bfloat16(f);
    return u.s;
}
__device__ __forceinline__ float bs2f(unsigned short s) {
    union { unsigned int u; float f; } v;
    v.u = ((unsigned int)s) << 16;
    return v.f;
}
__device__ __forceinline__ float sigmoidf_(float x) { return 1.0f / (1.0f + expf(-x)); }
__device__ __forceinline__ float gelu_exact(float x) {
    return 0.5f * x * (1.0f + erff(x * 0.7071067811865476f));
}

// ---------------------------------------------------------------------------
// K0: weight prep (blocks 0-255) + slots init / iter-0 q (blocks 256-511).
// Unchanged, proven round 7/8.
// ---------------------------------------------------------------------------
__global__ __launch_bounds__(256) void prep_init(
    const float* __restrict__ Wp, const float* __restrict__ Wk,
    const float* __restrict__ Wv, const float* __restrict__ W_ih,
    const float* __restrict__ W_hh,
    const float* __restrict__ noise, const float* __restrict__ mu,
    const float* __restrict__ lsig,
    const float* __restrict__ g_slots, const float* __restrict__ b_slots,
    const float* __restrict__ Wq, const float* __restrict__ bq,
    ushort_t* __restrict__ WpT, ushort_t* __restrict__ WkT,
    ushort_t* __restrict__ WvT, float* __restrict__ WTih,
    float* __restrict__ WThh,
    float* __restrict__ slots, float* __restrict__ qbuf)
{
    __shared__ float sl2[2][128];
    __shared__ float tt2[2][128];
    __shared__ float mrs2[2][2];
    const int t = threadIdx.x;

    if (blockIdx.x < 256) {
        int tid = blockIdx.x * 256 + t;             // 0..65535
        {
            int c = tid >> 7, d = tid & 127;        // coalesced read of Wp
            WpT[d * 512 + c] = f2bs(Wp[tid]);
        }
        if (tid < 16384) {
            int c = tid >> 7, d = tid & 127;
            WkT[d * 128 + c] = f2bs(Wk[tid]);
            WvT[d * 128 + c] = f2bs(Wv[tid]);
        }
        if (tid < 49152) {
            int j = tid >> 7, c = tid & 127;        // coalesced read of W_ih
            WTih[c * 384 + j] = W_ih[tid];
            WThh[c * 384 + j] = W_hh[tid];
        }
        return;
    }

    const int lr = t >> 7, lt = t & 127;
    const int row = ((blockIdx.x - 256) << 1) | lr;   // 0..511 = b*8+k
    const int b = row >> 3;
    const int kd = (row & 7) * 128 + lt;
    float sv = mu[kd] + expf(lsig[kd]) * noise[b * 1024 + kd];
    slots[(size_t)row * D_ + lt] = sv;
    sl2[lr][lt] = sv;
    __syncthreads();
    if (lt < 64) {
        float v0 = sl2[lr][lt], v1 = sl2[lr][lt + 64];
        float s = v0 + v1, s2 = v0 * v0 + v1 * v1;
        for (int off = 32; off > 0; off >>= 1) {
            s += __shfl_down(s, off, 64);
            s2 += __shfl_down(s2, off, 64);
        }
        if (lt == 0) {
            float mean = s * (1.f / 128.f);
            float var = s2 * (1.f / 128.f) - mean * mean;
            mrs2[lr][0] = mean; mrs2[lr][1] = rsqrtf(var + 1e-5f);
        }
    }
    __syncthreads();
    tt2[lr][lt] = (sl2[lr][lt] - mrs2[lr][0]) * mrs2[lr][1] * g_slots[lt] + b_slots[lt];
    __syncthreads();
    float a = bq[lt];
    for (int c = 0; c < 128; ++c) a = fmaf(tt2[lr][c], Wq[(size_t)c * D_ + lt], a);
    qbuf[(size_t)row * D_ + lt] = a;
}

// ---------------------------------------------------------------------------
// K1+K2 fused, v3. Phase 1 returns to STAGED x (round-8's direct fragment
// loads touched 4-16 cache lines per instr -> latency-bound, 94us), but with
// a bank-exact layout:
//   Alf[c][n] fp32, pitch 69 (odd dwords):
//     - stage writes: nn consecutive per wave -> bank stride 1 -> free
//     - fragment reads: 16x ds_read_b32; rows = 16 consecutive banks,
//       quad offset 552q%32 = {0,8,16,24} -> exactly 2 lanes/bank (floor)
//   f2bs applied per-read in-register -> bit-identical MFMA inputs.
// Alf unioned with phase-2's Bv2 (phase-disjoint, barrier-separated):
// LDS = 38.9KB -> 4 blocks/CU -> grid 1024 = one full co-resident wave.
// Phase 2 unchanged (proven round 7/8).
// ---------------------------------------------------------------------------
__global__ __launch_bounds__(256) void proj_kv(
    const float* __restrict__ x, const ushort_t* __restrict__ WpT,
    const float* __restrict__ bp, const float* __restrict__ g_in,
    const float* __restrict__ b_in,
    const ushort_t* __restrict__ WkT, const float* __restrict__ bk,
    const ushort_t* __restrict__ WvT, const float* __restrict__ bv,
    ushort_t* __restrict__ kout, ushort_t* __restrict__ vout)
{
    __shared__ __align__(16) ushort_t Bl[128 * 40];   // WpT chunks (ph1), WkT (ph2)
    __shared__ __align__(16) char un[10240];          // Alf[32][69] f32 (ph1) U Bv2[128*40] ush (ph2)
    __shared__ __align__(16) ushort_t A2[64 * 136];   // LN'd inputs, bf16
    __shared__ float red[64][2][2];
    float* Alf = (float*)un;
    ushort_t* Bv2 = (ushort_t*)un;

    const int t = threadIdx.x;
    const int b = blockIdx.x >> 4;
    const int n0 = (blockIdx.x & 15) << 6;
    const int w = t >> 6, lane = t & 63;
    const int quad = lane >> 4, m = lane & 15;
    const int rowoff = (w >> 1) << 5;   // 0 / 32
    const int coloff = (w & 1) << 6;    // 0 / 64

    // ================= phase 1: proj + LN (staged, bank-exact) =============
    f32x4 acc[2][4];
#pragma unroll
    for (int r = 0; r < 2; ++r)
#pragma unroll
        for (int c = 0; c < 4; ++c) acc[r][c] = (f32x4){0.f, 0.f, 0.f, 0.f};

    const float* xb = x + (size_t)b * (C_ * N_);
    for (int c0 = 0; c0 < C_; c0 += 32) {
        // stage x chunk [32 c][64 n] as fp32, pitch 69: coalesced global,
        // bank-stride-1 LDS writes (free)
#pragma unroll
        for (int i = 0; i < 8; ++i) {
            int idx = t + (i << 8);            // 0..2047
            int cc = idx >> 6, nn = idx & 63;
            Alf[cc * 69 + nn] = xb[(size_t)(c0 + cc) * N_ + n0 + nn];
        }
#pragma unroll
        for (int i = 0; i < 2; ++i) {
            int idx = t + (i << 8);           // 0..511
            int d = idx >> 2, seg = idx & 3;  // 128 rows x 4 segs of 8
            *(bf16x8*)&Bl[d * 40 + seg * 8] =
                *(const bf16x8*)&WpT[d * 512 + c0 + seg * 8];
        }
        __syncthreads();
        bf16x8 af[2], bfr[4];
#pragma unroll
        for (int r = 0; r < 2; ++r) {
            union { ushort_t u[8]; bf16x8 v; } pk;
            const int row = rowoff + 16 * r + m;
#pragma unroll
            for (int j = 0; j < 8; ++j)
                pk.u[j] = f2bs(Alf[(quad * 8 + j) * 69 + row]);
            af[r] = pk.v;
        }
#pragma unroll
        for (int c = 0; c < 4; ++c)
            bfr[c] = *(const bf16x8*)&Bl[(coloff + 16 * c + m) * 40 + quad * 8];
#pragma unroll
        for (int r = 0; r < 2; ++r)
#pragma unroll
            for (int c = 0; c < 4; ++c)
                acc[r][c] = __builtin_amdgcn_mfma_f32_16x16x32_bf16(af[r], bfr[c], acc[r][c], 0, 0, 0);
        __syncthreads();
    }
    float gv[4], bvv[4], bpv[4];
#pragma unroll
    for (int c = 0; c < 4; ++c) {
        int col = coloff + 16 * c + m;
        bpv[c] = bp[col]; gv[c] = g_in[col]; bvv[c] = b_in[col];
    }
#pragma unroll
    for (int r = 0; r < 2; ++r)
#pragma unroll
        for (int c = 0; c < 4; ++c)
#pragma unroll
            for (int g = 0; g < 4; ++g) acc[r][c][g] += bpv[c];

#pragma unroll
    for (int r = 0; r < 2; ++r) {
#pragma unroll
        for (int g = 0; g < 4; ++g) {
            float s = 0.f, s2 = 0.f;
#pragma unroll
            for (int c = 0; c < 4; ++c) { float v = acc[r][c][g]; s += v; s2 += v * v; }
#pragma unroll
            for (int off = 1; off < 16; off <<= 1) {
                s += __shfl_xor(s, off, 64);
                s2 += __shfl_xor(s2, off, 64);
            }
            if (m == 0) {
                int row = rowoff + 16 * r + quad * 4 + g;
                red[row][w & 1][0] = s;
                red[row][w & 1][1] = s2;
            }
        }
    }
    __syncthreads();
#pragma unroll
    for (int r = 0; r < 2; ++r) {
#pragma unroll
        for (int g = 0; g < 4; ++g) {
            int row = rowoff + 16 * r + quad * 4 + g;
            float s = red[row][0][0] + red[row][1][0];
            float s2 = red[row][0][1] + red[row][1][1];
            float mean = s * (1.f / 128.f);
            float var = s2 * (1.f / 128.f) - mean * mean;
            float rs = rsqrtf(var + 1e-5f);
#pragma unroll
            for (int c = 0; c < 4; ++c) {
                int col = coloff + 16 * c + m;
                float v = (acc[r][c][g] - mean) * rs * gv[c] + bvv[c];
                A2[row * 136 + col] = f2bs(v);
            }
        }
    }
    // A2/Bv2 hazards covered by phase-2's first staging barrier (all A2
    // writes and last Alf reads precede it on every thread).

    // ================= phase 2: k/v MFMA (proven) =========================
    const int is_v = w >> 1;
    const int rowoff2 = (w & 1) << 5;
    f32x4 acc2[2][8];
#pragma unroll
    for (int r = 0; r < 2; ++r)
#pragma unroll
        for (int c = 0; c < 8; ++c) acc2[r][c] = (f32x4){0.f, 0.f, 0.f, 0.f};

    for (int c0 = 0; c0 < D_; c0 += 32) {
#pragma unroll
        for (int i = 0; i < 2; ++i) {
            int idx = t + (i << 8);
            int d = idx >> 2, seg = idx & 3;
            *(bf16x8*)&Bl[d * 40 + seg * 8] =
                *(const bf16x8*)&WkT[d * 128 + c0 + seg * 8];
            *(bf16x8*)&Bv2[d * 40 + seg * 8] =
                *(const bf16x8*)&WvT[d * 128 + c0 + seg * 8];
        }
        __syncthreads();
        const ushort_t* Bsrc = is_v ? Bv2 : Bl;
        bf16x8 af[2], bfr[8];
#pragma unroll
        for (int r = 0; r < 2; ++r)
            af[r] = *(const bf16x8*)&A2[(rowoff2 + 16 * r + m) * 136 + c0 + quad * 8];
#pragma unroll
        for (int c = 0; c < 8; ++c)
            bfr[c] = *(const bf16x8*)&Bsrc[(16 * c + m) * 40 + quad * 8];
#pragma unroll
        for (int r = 0; r < 2; ++r)
#pragma unroll
            for (int c = 0; c < 8; ++c)
                acc2[r][c] = __builtin_amdgcn_mfma_f32_16x16x32_bf16(af[r], bfr[c], acc2[r][c], 0, 0, 0);
        __syncthreads();
    }
    const float* bias = is_v ? bv : bk;
    ushort_t* dst = is_v ? vout : kout;
    float bval[8];
#pragma unroll
    for (int c = 0; c < 8; ++c) bval[c] = bias[16 * c + m];
#pragma unroll
    for (int r = 0; r < 2; ++r) {
#pragma unroll
        for (int g = 0; g < 4; ++g) {
            int row = rowoff2 + 16 * r + quad * 4 + g;
            size_t base = ((size_t)b * N_ + n0 + row) * D_;
#pragma unroll
            for (int c = 0; c < 8; ++c)
                dst[base + 16 * c + m] = f2bs(acc2[r][c][g] + bval[c]);
        }
    }
}

// ---------------------------------------------------------------------------
// K4: attn + PV per n-quarter (unchanged round 8: pitch-128 kvt with XOR
// swizzle on both stagings and both read sites; passed, conflicts ~10x down).
// ---------------------------------------------------------------------------
__global__ __launch_bounds__(512, 2) void attn_pv(
    const ushort_t* __restrict__ kb, const ushort_t* __restrict__ vb,
    const float* __restrict__ qbuf,
    float* __restrict__ S_part, float* __restrict__ upd_part,
    float* __restrict__ out_attn, int last)
{
    __shared__ __align__(16) char scratch[69632];   // kvt[256][128] ush U red[64][132] f32
    __shared__ __align__(16) float at8[8][264];     // logits -> attn (quarter)
    __shared__ __align__(16) float qs[8][132];
    __shared__ float red2[4][8];
    ushort_t* kvt = (ushort_t*)scratch;
    float* red = (float*)scratch;

    const int t = threadIdx.x;
    const int qd = blockIdx.x, b = blockIdx.y;
    const int nbase = qd << 8;
    const int wv = t >> 6, lane = t & 63;
    const float SCALE = 0.08838834764831845f;

    // q: 4 KB, coalesced
    for (int i = t; i < 1024; i += 512)
        qs[i >> 7][i & 127] = qbuf[(size_t)b * 1024 + i];
    // stage k-quarter (coalesced bf16x8, swizzled dest)
#pragma unroll
    for (int i = 0; i < 8; ++i) {
        int idx = t + (i << 9);            // 0..4095
        int rr = idx >> 4, u8 = (idx & 15) << 3;
        int su8 = u8 ^ ((rr & 15) << 3);
        *(bf16x8*)&kvt[rr * 128 + su8] =
            *(const bf16x8*)&kb[((size_t)b * N_ + nbase + rr) * D_ + u8];
    }
    __syncthreads();

    // logits: thread (rr = t&255, kh = t>>8) -> 4 k-dots for its n-row
    {
        const int rr = t & 255, kh = t >> 8;
        float acc[4] = {0.f, 0.f, 0.f, 0.f};
        for (int c0 = 0; c0 < 128; c0 += 8) {
            bf16x8 kr = *(const bf16x8*)&kvt[rr * 128 + (c0 ^ ((rr & 15) << 3))];
            float kf[8];
#pragma unroll
            for (int j = 0; j < 8; ++j) kf[j] = bs2f((ushort_t)kr[j]);
#pragma unroll
            for (int kk = 0; kk < 4; ++kk) {
                f32x4 qa = *(const f32x4*)&qs[4 * kh + kk][c0];
                f32x4 qb = *(const f32x4*)&qs[4 * kh + kk][c0 + 4];
                acc[kk] = fmaf(qa[0], kf[0], acc[kk]);
                acc[kk] = fmaf(qa[1], kf[1], acc[kk]);
                acc[kk] = fmaf(qa[2], kf[2], acc[kk]);
                acc[kk] = fmaf(qa[3], kf[3], acc[kk]);
                acc[kk] = fmaf(qb[0], kf[4], acc[kk]);
                acc[kk] = fmaf(qb[1], kf[5], acc[kk]);
                acc[kk] = fmaf(qb[2], kf[6], acc[kk]);
                acc[kk] = fmaf(qb[3], kf[7], acc[kk]);
            }
        }
#pragma unroll
        for (int kk = 0; kk < 4; ++kk)
            at8[4 * kh + kk][rr] = acc[kk];
    }
    __syncthreads();

    // softmax over k per local n (t<256) + per-wave S partials
    if (t < 256) {
        float l[8];
#pragma unroll
        for (int k = 0; k < 8; ++k) l[k] = at8[k][t] * SCALE;
        float mx = l[0];
#pragma unroll
        for (int k = 1; k < 8; ++k) mx = fmaxf(mx, l[k]);
        float e[8], ssum = 0.f;
#pragma unroll
        for (int k = 0; k < 8; ++k) { e[k] = expf(l[k] - mx); ssum += e[k]; }
        float inv = 1.f / ssum;
        float p[8];
#pragma unroll
        for (int k = 0; k < 8; ++k) {
            p[k] = e[k] * inv;
            at8[k][t] = p[k];
            if (last) out_attn[((size_t)b * K_ + k) * N_ + nbase + t] = p[k];
        }
#pragma unroll
        for (int k = 0; k < 8; ++k) {
            float v = p[k];
            for (int off = 32; off > 0; off >>= 1) v += __shfl_down(v, off, 64);
            if (lane == 0) red2[wv][k] = v;
        }
    }
    __syncthreads();
    if (t < 8)
        S_part[((size_t)b * 4 + qd) * 8 + t] =
            red2[0][t] + red2[1][t] + red2[2][t] + red2[3][t];

    // stage v-quarter (kvt reuse, same swizzle)
#pragma unroll
    for (int i = 0; i < 8; ++i) {
        int idx = t + (i << 9);
        int rr = idx >> 4, u8 = (idx & 15) << 3;
        int su8 = u8 ^ ((rr & 15) << 3);
        *(bf16x8*)&kvt[rr * 128 + su8] =
            *(const bf16x8*)&vb[((size_t)b * N_ + nbase + rr) * D_ + u8];
    }
    __syncthreads();

    // PV: upd quarter-partial = attn(quarter) @ v(quarter)
    {
        float acc[8][4];
#pragma unroll
        for (int k = 0; k < 8; ++k)
#pragma unroll
            for (int j = 0; j < 4; ++j) acc[k][j] = 0.f;
        const int d4 = (t & 31) * 4, s = t >> 5;
#pragma unroll
        for (int i2 = 0; i2 < 4; ++i2) {
            const int nn = (s << 4) + (i2 << 2);
            float vf[4][4];
#pragma unroll
            for (int i = 0; i < 4; ++i) {
                int row = nn + i;
                int scol = (d4 & 7) | ((d4 & 0x78) ^ ((row & 15) << 3));
                ushort4 v4 = *(const ushort4*)&kvt[row * 128 + scol];
                vf[i][0] = bs2f(v4.x); vf[i][1] = bs2f(v4.y);
                vf[i][2] = bs2f(v4.z); vf[i][3] = bs2f(v4.w);
            }
#pragma unroll
            for (int k = 0; k < 8; ++k) {
                f32x4 a4 = *(const f32x4*)&at8[k][nn];
#pragma unroll
                for (int i = 0; i < 4; ++i) {
                    acc[k][0] = fmaf(a4[i], vf[i][0], acc[k][0]);
                    acc[k][1] = fmaf(a4[i], vf[i][1], acc[k][1]);
                    acc[k][2] = fmaf(a4[i], vf[i][2], acc[k][2]);
                    acc[k][3] = fmaf(a4[i], vf[i][3], acc[k][3]);
                }
            }
        }
        __syncthreads();   // kvt reads done; scratch becomes red[]
#pragma unroll
        for (int k = 0; k < 8; ++k)
#pragma unroll
            for (int j = 0; j < 4; ++j)
                acc[k][j] += __shfl_xor(acc[k][j], 32, 64);
        if (lane < 32) {
#pragma unroll
            for (int k = 0; k < 8; ++k)
#pragma unroll
                for (int j = 0; j < 4; ++j)
                    red[(wv * 8 + k) * 132 + lane * 4 + j] = acc[k][j];
        }
        __syncthreads();
        for (int i = t; i < 1024; i += 512) {
            int k = i >> 7, d = i & 127;
            float ssum = 0.f;
#pragma unroll
            for (int w = 0; w < 8; ++w) ssum += red[(w * 8 + k) * 132 + d];
            upd_part[((size_t)b * 4 + qd) * 1024 + i] = ssum;
        }
    }
}

// ---------------------------------------------------------------------------
// K5: GRU + LN + MLP + residual + next-q (unchanged, proven round 6/7/8).
// ---------------------------------------------------------------------------
__global__ __launch_bounds__(256) void gru_mlp_q(
    const float* __restrict__ upd_part, const float* __restrict__ S_part,
    float* __restrict__ slots,
    const float* __restrict__ WTih, const float* __restrict__ WThh,
    const float* __restrict__ b_ih, const float* __restrict__ b_hh,
    const float* __restrict__ W1, const float* __restrict__ b1,
    const float* __restrict__ W2, const float* __restrict__ b2,
    const float* __restrict__ g_mlp, const float* __restrict__ b_mlp,
    const float* __restrict__ g_slots, const float* __restrict__ b_slots,
    const float* __restrict__ Wq, const float* __restrict__ bq,
    float* __restrict__ qbuf,
    float* __restrict__ out_slots, int final_iter)
{
    __shared__ float u[128], h[128], gx[384], gh[384], sn[128], tt[128], hm[256];
    __shared__ float mrs[2];
    const int t = threadIdx.x;
    const int row = blockIdx.x;           // b*8 + k
    const int b = row >> 3, k = row & 7;
    if (t < 128) {
        size_t sb = (size_t)b * 4;
        float S = S_part[(sb + 0) * 8 + k] + S_part[(sb + 1) * 8 + k]
                + S_part[(sb + 2) * 8 + k] + S_part[(sb + 3) * 8 + k];
        float inv = 1.0f / (S + 1e-8f);
        int i = k * 128 + t;
        float up = upd_part[(sb + 0) * 1024 + i] + upd_part[(sb + 1) * 1024 + i]
                 + upd_part[(sb + 2) * 1024 + i] + upd_part[(sb + 3) * 1024 + i];
        u[t] = up * inv;
        h[t] = slots[(size_t)row * D_ + t];
    }
    __syncthreads();
    {
        int j = t;
        float ax = 0.f, ah = 0.f;
        for (int c = 0; c < 128; ++c) {
            float uc = u[c], hc = h[c];
            ax = fmaf(uc, WTih[(size_t)c * 384 + j], ax);
            ah = fmaf(hc, WThh[(size_t)c * 384 + j], ah);
        }
        gx[j] = ax + b_ih[j];
        gh[j] = ah + b_hh[j];
    }
    if (t < 128) {
        int j = 256 + t;
        float ax = 0.f, ah = 0.f;
        for (int c = 0; c < 128; ++c) {
            float uc = u[c], hc = h[c];
            ax = fmaf(uc, WTih[(size_t)c * 384 + j], ax);
            ah = fmaf(hc, WThh[(size_t)c * 384 + j], ah);
        }
        gx[j] = ax + b_ih[j];
        gh[j] = ah + b_hh[j];
    }
    __syncthreads();
    if (t < 128) {
        float r = sigmoidf_(gx[t] + gh[t]);
        float z = sigmoidf_(gx[t + 128] + gh[t + 128]);
        float nv = tanhf(gx[t + 256] + r * gh[t + 256]);
        sn[t] = (1.0f - z) * nv + z * h[t];
    }
    __syncthreads();
    if (t < 64) {
        float v0 = sn[t], v1 = sn[t + 64];
        float s = v0 + v1, s2 = v0 * v0 + v1 * v1;
        for (int off = 32; off > 0; off >>= 1) {
            s += __shfl_down(s, off, 64);
            s2 += __shfl_down(s2, off, 64);
        }
        if (t == 0) {
            float mean = s * (1.f / 128.f);
            float var = s2 * (1.f / 128.f) - mean * mean;
            mrs[0] = mean; mrs[1] = rsqrtf(var + 1e-5f);
        }
    }
    __syncthreads();
    if (t < 128) tt[t] = (sn[t] - mrs[0]) * mrs[1] * g_mlp[t] + b_mlp[t];
    __syncthreads();
    {
        float a = 0.f;
        for (int c = 0; c < 128; ++c) a = fmaf(tt[c], W1[(size_t)c * 256 + t], a);
        hm[t] = gelu_exact(a + b1[t]);
    }
    __syncthreads();
    if (t < 128) {
        float a = sn[t] + b2[t];
        for (int j = 0; j < 256; ++j) a = fmaf(hm[j], W2[(size_t)j * D_ + t], a);
        slots[(size_t)row * D_ + t] = a;
        if (final_iter) out_slots[(size_t)row * D_ + t] = a;
        u[t] = a;                      // reuse u[] as new-slots buffer for q
    }
    __syncthreads();
    // ---- q for next iteration
    if (t < 64) {
        float v0 = u[t], v1 = u[t + 64];
        float s = v0 + v1, s2 = v0 * v0 + v1 * v1;
        for (int off = 32; off > 0; off >>= 1) {
            s += __shfl_down(s, off, 64);
            s2 += __shfl_down(s2, off, 64);
        }
        if (t == 0) {
            float mean = s * (1.f / 128.f);
            float var = s2 * (1.f / 128.f) - mean * mean;
            mrs[0] = mean; mrs[1] = rsqrtf(var + 1e-5f);
        }
    }
    __syncthreads();
    if (t < 128) tt[t] = (u[t] - mrs[0]) * mrs[1] * g_slots[t] + b_slots[t];
    __syncthreads();
    if (!final_iter && t < 128) {
        float a = bq[t];
        for (int c = 0; c < 128; ++c) a = fmaf(tt[c], Wq[(size_t)c * D_ + t], a);
        qbuf[(size_t)row * D_ + t] = a;
    }
}

// ---------------------------------------------------------------------------
extern "C" void kernel_launch(void* const* d_in, const int* in_sizes, int n_in,
                              void* d_out, int out_size, void* d_ws, size_t ws_size,
                              hipStream_t stream) {
    const float* x       = (const float*)d_in[0];
    const float* noise   = (const float*)d_in[1];
    const float* slot_mu = (const float*)d_in[2];
    const float* slot_ls = (const float*)d_in[3];
    const float* Wp      = (const float*)d_in[4];
    const float* bp      = (const float*)d_in[5];
    const float* g_in    = (const float*)d_in[6];
    const float* b_in    = (const float*)d_in[7];
    const float* Wq      = (const float*)d_in[8];
    const float* bq      = (const float*)d_in[9];
    const float* Wk      = (const float*)d_in[10];
    const float* bk      = (const float*)d_in[11];
    const float* Wv      = (const float*)d_in[12];
    const float* bv      = (const float*)d_in[13];
    const float* W_ih    = (const float*)d_in[14];
    const float* W_hh    = (const float*)d_in[15];
    const float* b_ih    = (const float*)d_in[16];
    const float* b_hh    = (const float*)d_in[17];
    const float* W1      = (const float*)d_in[18];
    const float* b1      = (const float*)d_in[19];
    const float* W2      = (const float*)d_in[20];
    const float* b2      = (const float*)d_in[21];
    const float* g_slots = (const float*)d_in[22];
    const float* b_slots = (const float*)d_in[23];
    const float* g_mlp   = (const float*)d_in[24];
    const float* b_mlp   = (const float*)d_in[25];

    float* out_slots = (float*)d_out;            // [64,8,128] fp32
    float* out_attn  = (float*)d_out + 65536;    // [64,8,1024] fp32

    // workspace layout (float units)
    float* wsf = (float*)d_ws;
    ushort_t* kb = (ushort_t*)(wsf + 4194304);             // 65536x128 bf16
    ushort_t* vb = (ushort_t*)(wsf + 8388608);             // 65536x128 bf16
    float* slots    = wsf + 12582912;   // 512*128
    float* qbuf     = wsf + 12648448;   // 512*128
    float* upd_part = wsf + 12713984;   // [64][4][8][128] = 262144
    float* S_part   = wsf + 12976128;   // [64][4][8] = 2048
    ushort_t* WpT = (ushort_t*)(wsf + 13304320);  // 128x512 bf16
    ushort_t* WkT = (ushort_t*)(wsf + 13337088);  // 128x128 bf16
    ushort_t* WvT = (ushort_t*)(wsf + 13345280);  // 128x128 bf16
    float* WTih = wsf + 13353472;    // 128x384 fp32
    float* WThh = wsf + 13402624;    // 128x384 fp32

    prep_init<<<dim3(512), dim3(256), 0, stream>>>(
        Wp, Wk, Wv, W_ih, W_hh, noise, slot_mu, slot_ls,
        g_slots, b_slots, Wq, bq,
        WpT, WkT, WvT, WTih, WThh, slots, qbuf);
    proj_kv<<<dim3(1024), dim3(256), 0, stream>>>(
        x, WpT, bp, g_in, b_in, WkT, bk, WvT, bv, kb, vb);

    for (int it = 0; it < 3; ++it) {
        int last = (it == 2) ? 1 : 0;
        attn_pv<<<dim3(4, 64), dim3(512), 0, stream>>>(
            kb, vb, qbuf, S_part, upd_part, out_attn, last);
        gru_mlp_q<<<dim3(512), dim3(256), 0, stream>>>(
            upd_part, S_part, slots, WTih, WThh, b_ih, b_hh,
            W1, b1, W2, b2, g_mlp, b_mlp, g_slots, b_slots,
            Wq, bq, qbuf, out_slots, last);
    }
}